// Round 4
// baseline (456.035 us; speedup 1.0000x reference)
//
#include <hip/hip_runtime.h>

#define NROWS 8192
#define DIM   128
#define PSTR  520    // k_prep LDS row stride (shorts)

typedef __attribute__((ext_vector_type(8))) short  short8;
typedef __attribute__((ext_vector_type(4))) float  floatx4;

// pack two fp32 -> two bf16 (RNE), low word = a
__device__ __forceinline__ unsigned pk_bf16(float a, float b) {
  unsigned ua = __float_as_uint(a);
  ua += 0x7fffu + ((ua >> 16) & 1u);
  unsigned ub = __float_as_uint(b);
  ub += 0x7fffu + ((ub >> 16) & 1u);
  return (ua >> 16) | (ub & 0xffff0000u);
}

__device__ __forceinline__ float inv_sqrt_d(float dv) {
  return 1.0f / (sqrtf(dv) + 1e-8f);
}

// ---- kernel 1: fused rowsum + bf16-tile conversion of A --------------------
// Tile layout: Abf[((iblk*256 + jblk)*64 + L)*8 + e], L = quad*16 + l15:
//   row i = iblk*16 + l15, col j = jblk*32 + quad*8 + e  (MFMA B-operand frag)
__global__ __launch_bounds__(256) void k_prep(const float* __restrict__ A,
                                              float* __restrict__ d,
                                              unsigned short* __restrict__ Abf) {
  __shared__ unsigned short B[16 * PSTR];   // 16.6 KB
  __shared__ float rsum[16 * 17];
  int iblk = blockIdx.x;            // 0..511
  int wb   = blockIdx.y;            // 0..15
  int i0   = iblk * 16;
  int jwin = wb * 512;
  int t = threadIdx.x;
  int r = t >> 4, l16 = t & 15;

  const float* ap = A + (size_t)(i0 + r) * NROWS + jwin + l16 * 8;
  float sum = 0.f;
#pragma unroll
  for (int it = 0; it < 4; ++it) {
    float4 lo = *(const float4*)(ap + it * 128);
    float4 hi = *(const float4*)(ap + it * 128 + 4);
    sum += (lo.x + lo.y) + (lo.z + lo.w) + (hi.x + hi.y) + (hi.z + hi.w);
    uint4 p = make_uint4(pk_bf16(lo.x, lo.y), pk_bf16(lo.z, lo.w),
                         pk_bf16(hi.x, hi.y), pk_bf16(hi.z, hi.w));
    *(uint4*)&B[r * PSTR + l16 * 8 + it * 128] = p;
  }
  rsum[r * 17 + l16] = sum;
  __syncthreads();
  if (t < 16) {
    float s2 = 0.f;
#pragma unroll
    for (int c = 0; c < 16; ++c) s2 += rsum[t * 17 + c];
    atomicAdd(&d[i0 + t], s2);
  }
  // tiled write: 16 tiles (jb), 16 threads each, 4 lane-slots per thread
  int jb = t >> 4, p = t & 15;
  unsigned short* tbase = Abf + ((size_t)iblk * 256 + wb * 16 + jb) * 512;
#pragma unroll
  for (int q = 0; q < 4; ++q) {
    uint4 v = *(const uint4*)&B[p * PSTR + jb * 32 + q * 8];
    *(uint4*)(tbase + (size_t)(q * 16 + p) * 8) = v;
  }
}

// ---- kernel 2: gT tiles: gTt tile[kblk][jblk], lane L: kout=kblk*16+(L&15),
//      j = jblk*32 + (L>>4)*8 + e   (MFMA A-operand frag), value s_j*fc[j][k]
__global__ __launch_bounds__(256) void k_fc(const float* __restrict__ V,
                                            const float* __restrict__ W,
                                            const float* __restrict__ b,
                                            const float* __restrict__ d,
                                            unsigned short* __restrict__ gTt) {
  __shared__ float Wl[DIM * DIM];          // 64 KB
  __shared__ float Vl[32 * DIM];           // 16 KB
  __shared__ unsigned short Fl[32 * DIM];  // 8 KB  [j_local][k]
  int r0 = blockIdx.x * 32;
  {
    const float4* Wg = (const float4*)W;
    float4* Wd = (float4*)Wl;
#pragma unroll
    for (int i = 0; i < DIM * DIM / 4 / 256; ++i)
      Wd[threadIdx.x + i * 256] = Wg[threadIdx.x + i * 256];
    const float4* Vg = (const float4*)(V + (size_t)r0 * DIM);
    float4* Vd = (float4*)Vl;
#pragma unroll
    for (int i = 0; i < 32 * DIM / 4 / 256; ++i)
      Vd[threadIdx.x + i * 256] = Vg[threadIdx.x + i * 256];
  }
  __syncthreads();

  int cg = threadIdx.x & 31;
  int rg = threadIdx.x >> 5;
  float acc[4][4] = {};
  for (int dd = 0; dd < DIM; ++dd) {
    float4 w = *(const float4*)&Wl[dd * DIM + cg * 4];
#pragma unroll
    for (int rr = 0; rr < 4; ++rr) {
      float v = Vl[(rg * 4 + rr) * DIM + dd];
      acc[rr][0] += v * w.x; acc[rr][1] += v * w.y;
      acc[rr][2] += v * w.z; acc[rr][3] += v * w.w;
    }
  }
  float bb[4], sv[4];
#pragma unroll
  for (int cc = 0; cc < 4; ++cc) bb[cc] = b[cg * 4 + cc];
#pragma unroll
  for (int rr = 0; rr < 4; ++rr) sv[rr] = inv_sqrt_d(d[r0 + rg * 4 + rr]);
#pragma unroll
  for (int rr = 0; rr < 4; ++rr)
#pragma unroll
    for (int cc = 0; cc < 4; cc += 2) {
      unsigned p = pk_bf16((acc[rr][cc]     + bb[cc])     * sv[rr],
                           (acc[rr][cc + 1] + bb[cc + 1]) * sv[rr]);
      *(unsigned*)&Fl[(rg * 4 + rr) * DIM + cg * 4 + cc] = p;
    }
  __syncthreads();

  int kblk = threadIdx.x >> 5, s5 = threadIdx.x & 31;
  int jblk = r0 >> 5;
#pragma unroll
  for (int h = 0; h < 2; ++h) {
    int L = s5 + h * 32;
    int l15 = L & 15, quad = L >> 4;
    int k = kblk * 16 + l15;
    unsigned w0 = (unsigned)Fl[(quad * 8 + 0) * DIM + k] | ((unsigned)Fl[(quad * 8 + 1) * DIM + k] << 16);
    unsigned w1 = (unsigned)Fl[(quad * 8 + 2) * DIM + k] | ((unsigned)Fl[(quad * 8 + 3) * DIM + k] << 16);
    unsigned w2 = (unsigned)Fl[(quad * 8 + 4) * DIM + k] | ((unsigned)Fl[(quad * 8 + 5) * DIM + k] << 16);
    unsigned w3 = (unsigned)Fl[(quad * 8 + 6) * DIM + k] | ((unsigned)Fl[(quad * 8 + 7) * DIM + k] << 16);
    *(uint4*)(gTt + ((size_t)(kblk * 256 + jblk) * 64 + L) * 8) = make_uint4(w0, w1, w2, w3);
  }
}

// ---- kernel 3: partial[ks][i][k] = sum_{j in slice} A_ij * g_jk ------------
// Block = 4 waves; wave w owns kout [w*32, w*32+32), block owns 32 i rows and
// a 2048-wide j slice. No LDS, no barriers; acc = 4 x 16x16 tiles per wave.
__global__ __launch_bounds__(256, 8) void k_spmm(const unsigned short* __restrict__ Abf,
                                                 const unsigned short* __restrict__ gTt,
                                                 float* __restrict__ partial) {
  int t = threadIdx.x, w = t >> 6, lane = t & 63;
  int bi = blockIdx.x >> 2, ks = blockIdx.x & 3;
  int kb0 = w * 2;

  const unsigned short* ab = Abf + (((size_t)(2 * bi) * 256 + ks * 64) * 64 + lane) * 8;
  const unsigned short* gb = gTt + (((size_t)kb0 * 256 + ks * 64) * 64 + lane) * 8;
  const size_t TSTR = 256 * 512;   // one iblk/kblk row of tiles, in shorts

  floatx4 acc[2][2];
#pragma unroll
  for (int ib = 0; ib < 2; ++ib)
#pragma unroll
    for (int kb = 0; kb < 2; ++kb)
      acc[ib][kb] = (floatx4){0.f, 0.f, 0.f, 0.f};

#pragma unroll 4
  for (int jb = 0; jb < 64; ++jb) {
    short8 a0 = *(const short8*)(ab);
    short8 a1 = *(const short8*)(ab + TSTR);
    short8 g0 = *(const short8*)(gb);
    short8 g1 = *(const short8*)(gb + TSTR);
    acc[0][0] = __builtin_amdgcn_mfma_f32_16x16x32_bf16(g0, a0, acc[0][0], 0, 0, 0);
    acc[0][1] = __builtin_amdgcn_mfma_f32_16x16x32_bf16(g1, a0, acc[0][1], 0, 0, 0);
    acc[1][0] = __builtin_amdgcn_mfma_f32_16x16x32_bf16(g0, a1, acc[1][0], 0, 0, 0);
    acc[1][1] = __builtin_amdgcn_mfma_f32_16x16x32_bf16(g1, a1, acc[1][1], 0, 0, 0);
    ab += 512; gb += 512;
  }

  int l15 = lane & 15, quad = lane >> 4;
#pragma unroll
  for (int ib = 0; ib < 2; ++ib)
#pragma unroll
    for (int kb = 0; kb < 2; ++kb) {
      float* p = partial + ((size_t)(ks * 256 + bi) * 32 + ib * 16 + l15) * 128
                         + (kb0 + kb) * 16 + quad * 4;
      *(float4*)p = make_float4(acc[ib][kb][0], acc[ib][kb][1],
                                acc[ib][kb][2], acc[ib][kb][3]);
    }
}

// ---- kernel 4: out[i][k] = s_i * sum_ks partial[ks][i][k] ------------------
__global__ __launch_bounds__(256) void k_reduce(const float* __restrict__ partial,
                                                const float* __restrict__ d,
                                                float* __restrict__ out) {
  int g = blockIdx.x * 256 + threadIdx.x;    // 0..262143
  int i = g >> 5, c4 = (g & 31) * 4;
  size_t base = (size_t)i * 128 + c4;
  const size_t kstr = (size_t)256 * 32 * 128;
  float4 a  = *(const float4*)(partial + base);
  float4 bq = *(const float4*)(partial + base + kstr);
  float4 c  = *(const float4*)(partial + base + 2 * kstr);
  float4 dq = *(const float4*)(partial + base + 3 * kstr);
  float si = inv_sqrt_d(d[i]);
  float4 r;
  r.x = si * (a.x + bq.x + c.x + dq.x);
  r.y = si * (a.y + bq.y + c.y + dq.y);
  r.z = si * (a.z + bq.z + c.z + dq.z);
  r.w = si * (a.w + bq.w + c.w + dq.w);
  *(float4*)(out + base) = r;
}

extern "C" void kernel_launch(void* const* d_in, const int* in_sizes, int n_in,
                              void* d_out, int out_size, void* d_ws, size_t ws_size,
                              hipStream_t stream) {
  const float* values    = (const float*)d_in[0];
  const float* adjacency = (const float*)d_in[1];
  const float* W         = (const float*)d_in[2];
  const float* b         = (const float*)d_in[3];
  float* out = (float*)d_out;

  char* ws = (char*)d_ws;
  float* d            = (float*)ws;                         // 32 KB
  unsigned short* gTt = (unsigned short*)(ws + 65536);      // 2 MB
  float* partial      = (float*)(ws + 65536 + 2097152);     // 16 MB
  unsigned short* Abf = (unsigned short*)(ws + 33554432);   // 128 MB

  hipMemsetAsync(d, 0, NROWS * sizeof(float), stream);
  k_prep<<<dim3(512, 16), 256, 0, stream>>>(adjacency, d, Abf);
  k_fc<<<NROWS / 32, 256, 0, stream>>>(values, W, b, d, gTt);
  k_spmm<<<1024, 256, 0, stream>>>(Abf, gTt, partial);
  k_reduce<<<NROWS * 32 / 256, 256, 0, stream>>>(partial, d, out);
}